// Round 1
// baseline (70649.487 us; speedup 1.0000x reference)
//
#include <hip/hip_runtime.h>
#include <hip/hip_fp16.h>

// LSTM (S=16384, I=64, H=1024) -> ReLU -> FC(1024->128) -> ReLU -> FC(128->1), last step only.
// Wave-autonomous persistent design: 512 single-wave blocks, each wave owns 2 h-columns
// (8 gate rows) with W_hh register-resident. Per-step device-wide h broadcast via
// self-validating 4-byte (tag16, fp16) words, relaxed agent-scope atomics.
// NO barriers, NO LDS: each wave polls the full 1024-word h vector directly with
// perfectly-coalesced dword loads (lane c covers words s*256+u*64+c), computes its
// gates, activates on lanes 0-1, and stores 2 adjacent words. Critical path =
// store -> LLC -> detect -> 128 FMA + butterfly + activation -> store.

#define S_LEN 16384
#define I_DIM 64
#define H_DIM 1024
#define NWAVE 512     // one wave per block, 2 h-columns per wave

__device__ __forceinline__ float sigmoidf_(float x) { return 1.0f / (1.0f + __expf(-x)); }
__device__ __forceinline__ float tanh_fast(float x) { return 1.0f - 2.0f / (__expf(2.0f * x) + 1.0f); }

__global__ __launch_bounds__(64, 1) void lstm_wave(
    const float* __restrict__ xseq,   // [S, 64]
    const float* __restrict__ W_ih,   // [4096, 64]
    const float* __restrict__ W_hh,   // [4096, 1024]
    const float* __restrict__ b_ih,   // [4096]
    const float* __restrict__ b_hh,   // [4096]
    unsigned* __restrict__ pairs)     // [2][1024] 4-B words (tag16<<16 | fp16 bits)
{
    const int wv   = blockIdx.x;      // wave id 0..511
    const int c    = threadIdx.x;     // lane 0..63
    const int col0 = 2 * wv;          // this wave's first h-column

    // ---- one-time: weights into registers ----
    // Lane c's h-slice is columns { s*256 + u*64 + c : s,u in 0..3 } (coalesced polls).
    // wh[r][s*4+u] matches that slice for gate-row r = q*2 + j (gate q, col col0+j).
    float wh[8][16];
    float wi[8];
    #pragma unroll
    for (int r = 0; r < 8; ++r) {
        const int q = r >> 1, j = r & 1;
        const size_t row = (size_t)q * H_DIM + col0 + j;
        const float* wr = W_hh + row * H_DIM;
        #pragma unroll
        for (int s = 0; s < 4; ++s)
            #pragma unroll
            for (int u = 0; u < 4; ++u)
                wh[r][s * 4 + u] = wr[s * 256 + u * 64 + c];
        wi[r] = W_ih[row * I_DIM + c];
    }
    float bsum[4];
    {
        const int mycol = col0 + (c & 1);   // lanes 0/1 use it; others harmless
        #pragma unroll
        for (int q = 0; q < 4; ++q)
            bsum[q] = b_ih[q * H_DIM + mycol] + b_hh[q * H_DIM + mycol];
    }

    float cst = 0.0f;                 // cell state for own column (lanes 0,1)
    float xv  = xseq[c];              // x_0
    unsigned pk[4][4];                // polled h words (h_{t-1}) for next iteration

    for (int t = 0; t < S_LEN; ++t) {
        // ---- gates: W_ih . x_t (+ W_hh . h_{t-1} for t>0) ----
        float acc[8];
        #pragma unroll
        for (int r = 0; r < 8; ++r) acc[r] = wi[r] * xv;

        if (t > 0) {
            #pragma unroll
            for (int s = 0; s < 4; ++s) {
                #pragma unroll
                for (int u = 0; u < 4; ++u) {
                    const float hv = __half2float(
                        __ushort_as_half((unsigned short)(pk[s][u] & 0xFFFFu)));
                    #pragma unroll
                    for (int r = 0; r < 8; ++r)
                        acc[r] = fmaf(wh[r][s * 4 + u], hv, acc[r]);
                }
            }
        }

        // ---- full-wave butterfly reduction (8 row sums) ----
        #pragma unroll
        for (int r = 0; r < 8; ++r) {
            #pragma unroll
            for (int off = 32; off > 0; off >>= 1)
                acc[r] += __shfl_xor(acc[r], off, 64);
        }

        // ---- activations + state update + publish (lanes 0,1 -> 2 adjacent words) ----
        if (c < 2) {
            const float a_i = (c & 1) ? acc[1] : acc[0];
            const float a_f = (c & 1) ? acc[3] : acc[2];
            const float a_g = (c & 1) ? acc[5] : acc[4];
            const float a_o = (c & 1) ? acc[7] : acc[6];
            const float ig = sigmoidf_(a_i + bsum[0]);
            const float fg = sigmoidf_(a_f + bsum[1]);
            const float gg = tanh_fast (a_g + bsum[2]);
            const float og = sigmoidf_(a_o + bsum[3]);
            cst = fg * cst + ig * gg;
            const float h = og * tanh_fast(cst);
            const unsigned pkv = ((unsigned)(t + 1) << 16) |
                                 (unsigned)__half_as_ushort(__float2half(h));
            __hip_atomic_store(&pairs[((size_t)(t & 1) << 10) + col0 + c], pkv,
                               __ATOMIC_RELAXED, __HIP_MEMORY_SCOPE_AGENT);
        }

        if (t == S_LEN - 1) break;    // last h published; nothing left to read

        // prefetch x_{t+1} while we wait (no dependency on the poll)
        xv = xseq[(size_t)(t + 1) * I_DIM + c];

        // ---- poll h_t: 16 coalesced dword loads cover all 1024 words ----
        const unsigned* base = pairs + ((size_t)(t & 1) << 10) + c;
        const unsigned tgs = (unsigned)(t + 1) << 16;
        for (;;) {
            unsigned bad = 0;
            #pragma unroll
            for (int s = 0; s < 4; ++s)
                #pragma unroll
                for (int u = 0; u < 4; ++u) {
                    pk[s][u] = __hip_atomic_load(base + s * 256 + u * 64,
                                                 __ATOMIC_RELAXED, __HIP_MEMORY_SCOPE_AGENT);
                    bad |= pk[s][u] ^ tgs;
                }
            if (__all((bad >> 16) == 0)) break;   // every lane: all 16 tags match
        }
    }
}

// Final head: out = fc2( relu( fc1( relu(h_{S-1}) ) ) ). h_{S-1} is in pairs
// slot 1 ((S-1)&1). Kernel-boundary ordering makes plain loads safe.
__global__ __launch_bounds__(256) void fc_head(
    const unsigned* __restrict__ pairs,
    const float* __restrict__ fc1_w,  // [128, 1024]
    const float* __restrict__ fc1_b,  // [128]
    const float* __restrict__ fc2_w,  // [128]
    const float* __restrict__ fc2_b,  // [1]
    float* __restrict__ out)
{
    const int tid = threadIdx.x;
    __shared__ float4 hr4[H_DIM / 4];
    __shared__ float  partial[256];
    __shared__ float  r1[128];

    // extract fp16 h values from slot-1 pairs (4 pairs per thread)
    const uint4 pa = ((const uint4*)(pairs + H_DIM))[tid];
    float4 hv = make_float4(__half2float(__ushort_as_half((unsigned short)(pa.x & 0xFFFFu))),
                            __half2float(__ushort_as_half((unsigned short)(pa.y & 0xFFFFu))),
                            __half2float(__ushort_as_half((unsigned short)(pa.z & 0xFFFFu))),
                            __half2float(__ushort_as_half((unsigned short)(pa.w & 0xFFFFu))));
    hv.x = fmaxf(hv.x, 0.f); hv.y = fmaxf(hv.y, 0.f);
    hv.z = fmaxf(hv.z, 0.f); hv.w = fmaxf(hv.w, 0.f);
    hr4[tid] = hv;
    __syncthreads();

    const int row = tid & 127, half = tid >> 7;
    const float4* wrow = (const float4*)(fc1_w + (size_t)row * H_DIM) + half * 128;
    float a0 = 0.f, a1 = 0.f;
    #pragma unroll 4
    for (int i = 0; i < 128; i += 2) {
        const float4 w0 = wrow[i],     h0 = hr4[half * 128 + i];
        const float4 w1 = wrow[i + 1], h1 = hr4[half * 128 + i + 1];
        a0 += w0.x * h0.x + w0.y * h0.y + w0.z * h0.z + w0.w * h0.w;
        a1 += w1.x * h1.x + w1.y * h1.y + w1.z * h1.z + w1.w * h1.w;
    }
    partial[tid] = a0 + a1;
    __syncthreads();
    if (tid < 128) {
        const float s = partial[tid] + partial[tid + 128] + fc1_b[tid];
        r1[tid] = fmaxf(s, 0.f);
    }
    __syncthreads();
    if (tid < 64) {
        float v = r1[tid] * fc2_w[tid] + r1[tid + 64] * fc2_w[tid + 64];
        #pragma unroll
        for (int off = 32; off > 0; off >>= 1) v += __shfl_xor(v, off, 64);
        if (tid == 0) out[0] = v + fc2_b[0];
    }
}

extern "C" void kernel_launch(void* const* d_in, const int* in_sizes, int n_in,
                              void* d_out, int out_size, void* d_ws, size_t ws_size,
                              hipStream_t stream) {
    (void)in_sizes; (void)n_in; (void)out_size; (void)ws_size;
    const float* xseq  = (const float*)d_in[0];
    const float* W_ih  = (const float*)d_in[1];
    const float* W_hh  = (const float*)d_in[2];
    const float* b_ih  = (const float*)d_in[3];
    const float* b_hh  = (const float*)d_in[4];
    const float* fc1_w = (const float*)d_in[5];
    const float* fc1_b = (const float*)d_in[6];
    const float* fc2_w = (const float*)d_in[7];
    const float* fc2_b = (const float*)d_in[8];
    unsigned* pairs = (unsigned*)d_ws;

    lstm_wave<<<NWAVE, 64, 0, stream>>>(xseq, W_ih, W_hh, b_ih, b_hh, pairs);
    fc_head<<<1, 256, 0, stream>>>(pairs, fc1_w, fc1_b, fc2_w, fc2_b, (float*)d_out);
}